// Round 5
// baseline (4485.675 us; speedup 1.0000x reference)
//
#include <hip/hip_runtime.h>

// k-means (Lloyd), N=500000 D=64 K=256 ITERS=10, fp32.
// Round 4: D-split layout. Round 3's launch_bounds change failed to lift the
// 128-VGPR cap (VGPR_Count stayed 128, WRITE_SIZE stayed 161MB of spill).
// Instead, fit under the cap: lane pair (l, l^32) shares 2 points, each lane
// holds a 32-dim half (xv 64 regs total + acc 16 -> ~100 live, no spill).
// LDS broadcast-read count per point unchanged vs round 2 (1:8 ds:FMA).
// Dots completed with one shfl_xor(32) per acc per tile.

#define D 64
#define K 256
#define KT 8            // centroid tile (accumulators per point)
#define BLOCK 512       // 8 waves
#define NB_MAX 256      // one block per CU
#define ITERS 10
#define PART_STRIDE (D * K + K)          // floats per block partial (sums+counts)
#define SMEM_BYTES ((D * K + K + D * K + K) * 4)   // cent + csq + sums + cnt

// ---------------------------------------------------------------------------
// init: centroids0 = x[init_idx], csq[k] = ||c_k||^2
__global__ void init_gather(const float* __restrict__ x,
                            const int* __restrict__ idx,
                            float* __restrict__ cent,
                            float* __restrict__ csq) {
    int k = blockIdx.x;
    int d = threadIdx.x;
    float v = x[(size_t)idx[k] * D + d];
    cent[k * D + d] = v;
    float s = v * v;
    #pragma unroll
    for (int off = 32; off > 0; off >>= 1) s += __shfl_down(s, off);
    if (d == 0) csq[k] = s;
}

// ---------------------------------------------------------------------------
// fused assignment + accumulation. parts[b] = [D*K sums ([d][k]) | K counts]
__global__ __launch_bounds__(BLOCK, 1) void assign_fused(
        const float* __restrict__ x,
        const float* __restrict__ cent,
        const float* __restrict__ csq,
        float* __restrict__ parts,
        int N, int ppb) {
    extern __shared__ float smem[];
    float* s_cent = smem;                    // [K][D] 16384
    float* s_csq  = s_cent + D * K;          // K
    float* s_sums = s_csq + K;               // [D][K] 16384
    float* s_cnt  = s_sums + D * K;          // K

    const int tid = threadIdx.x;

    // stage centroids + csq, zero partials (float4 strided copies)
    {
        const float4* c4 = (const float4*)cent;
        float4* sc4 = (float4*)s_cent;
        #pragma unroll 1
        for (int i = tid; i < (D * K) / 4; i += BLOCK) sc4[i] = c4[i];
        if (tid < K / 4) ((float4*)s_csq)[tid] = ((const float4*)csq)[tid];
        float4 z = {0.f, 0.f, 0.f, 0.f};
        float4* ss4 = (float4*)s_sums;
        #pragma unroll 1
        for (int i = tid; i < (D * K) / 4; i += BLOCK) ss4[i] = z;
        if (tid >= K / 4 && tid < K / 2) ((float4*)s_cnt)[tid - K / 4] = z;
    }
    __syncthreads();

    const int w = tid >> 6;          // wave id (0..7)
    const int j = tid & 31;          // pair id within wave
    const int h32 = tid & 32;        // 0 or 32: which D-half this lane owns

    const int base = blockIdx.x * ppb;
    int lim = base + ppb;
    if (lim > N) lim = N;
    const int rounds = (ppb + BLOCK - 1) / BLOCK;   // 512 points per round

    #pragma unroll 1
    for (int r = 0; r < rounds; ++r) {
        // lane pair (j, h) of wave w shares points p0 and p1
        int p0 = base + r * BLOCK + w * 64 + j;
        int p1 = p0 + 32;
        bool v0 = p0 < lim, v1 = p1 < lim;
        int a0 = v0 ? p0 : base;
        int a1 = v1 ? p1 : base;

        float xv0[32], xv1[32];      // this lane's 32-dim half of each point
        {
            const float4* xp0 = (const float4*)(x + (size_t)a0 * D + h32);
            const float4* xp1 = (const float4*)(x + (size_t)a1 * D + h32);
            #pragma unroll
            for (int q = 0; q < 8; ++q) {
                float4 u = xp0[q];
                xv0[4 * q + 0] = u.x; xv0[4 * q + 1] = u.y;
                xv0[4 * q + 2] = u.z; xv0[4 * q + 3] = u.w;
                float4 t = xp1[q];
                xv1[4 * q + 0] = t.x; xv1[4 * q + 1] = t.y;
                xv1[4 * q + 2] = t.z; xv1[4 * q + 3] = t.w;
            }
        }
        float xq0 = 0.f, xq1 = 0.f;
        #pragma unroll
        for (int d = 0; d < 32; ++d) { xq0 += xv0[d] * xv0[d]; xq1 += xv1[d] * xv1[d]; }
        float xsq0 = xq0 + __shfl_xor(xq0, 32);
        float xsq1 = xq1 + __shfl_xor(xq1, 32);

        float best0 = 3.4e38f, best1 = 3.4e38f;
        int bk0 = 0, bk1 = 0;

        #pragma unroll 1
        for (int kt = 0; kt < K; kt += KT) {
            float acc0[KT], acc1[KT];
            #pragma unroll
            for (int t = 0; t < KT; ++t) { acc0[t] = 0.f; acc1[t] = 0.f; }

            #pragma unroll
            for (int d4 = 0; d4 < 32; d4 += 4) {
                #pragma unroll
                for (int t = 0; t < KT; ++t) {
                    float4 c = *(const float4*)&s_cent[(kt + t) * D + h32 + d4];
                    acc0[t] += c.x * xv0[d4 + 0];
                    acc0[t] += c.y * xv0[d4 + 1];
                    acc0[t] += c.z * xv0[d4 + 2];
                    acc0[t] += c.w * xv0[d4 + 3];
                    acc1[t] += c.x * xv1[d4 + 0];
                    acc1[t] += c.y * xv1[d4 + 1];
                    acc1[t] += c.z * xv1[d4 + 2];
                    acc1[t] += c.w * xv1[d4 + 3];
                }
            }
            float4 cqa = *(const float4*)&s_csq[kt];
            float4 cqb = *(const float4*)&s_csq[kt + 4];
            #pragma unroll
            for (int t = 0; t < KT; ++t) {
                float f0 = acc0[t] + __shfl_xor(acc0[t], 32);
                float f1 = acc1[t] + __shfl_xor(acc1[t], 32);
                float cq = (t < 4) ? (&cqa.x)[t] : (&cqb.x)[t - 4];
                float d0 = xsq0 - 2.0f * f0 + cq;
                if (d0 < best0) { best0 = d0; bk0 = kt + t; }
                float d1 = xsq1 - 2.0f * f1 + cq;
                if (d1 < best1) { best1 = d1; bk1 = kt + t; }
            }
        }

        // both halves hold identical bk; each adds its own 32 dims
        if (v0) {
            #pragma unroll
            for (int d = 0; d < 32; ++d)
                atomicAdd(&s_sums[(h32 + d) * K + bk0], xv0[d]);
            if (h32 == 0) atomicAdd(&s_cnt[bk0], 1.0f);
        }
        if (v1) {
            #pragma unroll
            for (int d = 0; d < 32; ++d)
                atomicAdd(&s_sums[(h32 + d) * K + bk1], xv1[d]);
            if (h32 == 0) atomicAdd(&s_cnt[bk1], 1.0f);
        }
    }

    __syncthreads();
    // non-atomic flush of this block's partials
    float* part = parts + (size_t)blockIdx.x * PART_STRIDE;
    float4* p4 = (float4*)part;
    const float4* ss4 = (const float4*)s_sums;
    #pragma unroll 1
    for (int i = tid; i < (D * K) / 4; i += BLOCK) p4[i] = ss4[i];
    if (tid < K / 4) p4[(D * K) / 4 + tid] = ((const float4*)s_cnt)[tid];
}

// ---------------------------------------------------------------------------
// reduce partials: gsums[j] = sum_b parts[b][j], j in [0, D*K+K)
__global__ void reduce_partials(const float* __restrict__ parts,
                                float* __restrict__ gsums, int nb) {
    int j = blockIdx.x * blockDim.x + threadIdx.x;
    if (j >= PART_STRIDE) return;
    float s = 0.f;
    #pragma unroll 4
    for (int b = 0; b < nb; ++b) s += parts[(size_t)b * PART_STRIDE + j];
    gsums[j] = s;
}

// ---------------------------------------------------------------------------
// finalize: new centroids + csq. gsums: [D*K sums ([d][k]) | K counts]
__global__ void finalize(float* __restrict__ cent,
                         const float* __restrict__ gsums,
                         float* __restrict__ csq) {
    int k = blockIdx.x;
    int d = threadIdx.x;
    float cnt = gsums[D * K + k];
    float s = gsums[d * K + k];
    float oldc = cent[k * D + d];
    float nc = (cnt > 0.0f) ? (s / cnt) : oldc;
    cent[k * D + d] = nc;
    float v = nc * nc;
    #pragma unroll
    for (int off = 32; off > 0; off >>= 1) v += __shfl_down(v, off);
    if (d == 0) csq[k] = v;
}

// ---------------------------------------------------------------------------
extern "C" void kernel_launch(void* const* d_in, const int* in_sizes, int n_in,
                              void* d_out, int out_size, void* d_ws, size_t ws_size,
                              hipStream_t stream) {
    const float* x = (const float*)d_in[0];
    const int* init_idx = (const int*)d_in[1];

    int N = in_sizes[0] / D;

    float* cent = (float*)d_out;            // K*D working + output buffer

    // ws layout: parts[nb][PART_STRIDE] | gsums[PART_STRIDE] | csq[K]
    size_t fixed = (size_t)(PART_STRIDE + K) * sizeof(float);
    int nb = NB_MAX;
    if (ws_size < fixed + (size_t)NB_MAX * PART_STRIDE * sizeof(float)) {
        size_t avail = (ws_size > fixed) ? (ws_size - fixed) : 0;
        nb = (int)(avail / (PART_STRIDE * sizeof(float)));
        if (nb < 1) nb = 1;   // (ws_size is expected to be ample; safety only)
    }
    float* parts = (float*)d_ws;
    float* gsums = parts + (size_t)nb * PART_STRIDE;
    float* csq = gsums + PART_STRIDE;

    // allow >64KB dynamic LDS
    hipFuncSetAttribute(reinterpret_cast<const void*>(assign_fused),
                        hipFuncAttributeMaxDynamicSharedMemorySize, SMEM_BYTES);

    init_gather<<<dim3(K), dim3(64), 0, stream>>>(x, init_idx, cent, csq);

    int ppb = (N + nb - 1) / nb;
    for (int it = 0; it < ITERS; ++it) {
        assign_fused<<<dim3(nb), dim3(BLOCK), SMEM_BYTES, stream>>>(
            x, cent, csq, parts, N, ppb);
        reduce_partials<<<dim3((PART_STRIDE + 255) / 256), dim3(256), 0, stream>>>(
            parts, gsums, nb);
        finalize<<<dim3(K), dim3(64), 0, stream>>>(cent, gsums, csq);
    }
}

// Round 7
// 2569.354 us; speedup vs baseline: 1.7458x; 1.7458x over previous
//
#include <hip/hip_runtime.h>

// k-means (Lloyd), N=500000 D=64 K=256 ITERS=10, fp32.
// Round 6: MFMA distances, fixed refine path. Round 5 failed (0.045 absmax)
// because (1) the candidate mask was built vs the RUNNING min -> refine always
// ran, and (2) refine used bf16-reconstructed centroids + a non-reference
// formula -> extra flips on near-tie points. Now: full-acc gmin first, mask vs
// final gmin+EPS, refine with exact fp32 global centroids and the round-2
// proven formula/order (xsq - 2*dot + csq, ascending d).

#define D 64
#define K 256
#define ITERS 10
#define BLOCK 512
#define NB_MAX 256
#define EPS 2e-2f
#define PART_STRIDE (K * D + K)   // 16640 floats per block partial
// LDS: chi 32KB + clo 32KB + csq 1KB + sums 64KB + cnt 1KB = 130KB
#define SMEM_BYTES ((16384 + 16384) * 2 + (256 + 16384 + 256) * 4)

typedef __attribute__((ext_vector_type(8))) short bf16x8;
typedef __attribute__((ext_vector_type(4))) float f32x4;
typedef __attribute__((ext_vector_type(4))) short short4v;

__device__ __forceinline__ unsigned short f2bf(float f) {
    unsigned u = __builtin_bit_cast(unsigned, f);
    u = u + 0x7FFFu + ((u >> 16) & 1u);   // RNE
    return (unsigned short)(u >> 16);
}
__device__ __forceinline__ float bf2f(unsigned short h) {
    unsigned u = ((unsigned)h) << 16;
    return __builtin_bit_cast(float, u);
}

// ---------------------------------------------------------------------------
// init: centroids0 = x[init_idx], csq[k] = ||c_k||^2
__global__ void init_gather(const float* __restrict__ x,
                            const int* __restrict__ idx,
                            float* __restrict__ cent,
                            float* __restrict__ csq) {
    int k = blockIdx.x;
    int d = threadIdx.x;
    float v = x[(size_t)idx[k] * D + d];
    cent[k * D + d] = v;
    float s = v * v;
    #pragma unroll
    for (int off = 32; off > 0; off >>= 1) s += __shfl_down(s, off);
    if (d == 0) csq[k] = s;
}

// ---------------------------------------------------------------------------
// fused assign (MFMA + exact refine) + accumulate.
// chi/clo LDS layout: [8 k-chunks][256 cents][8 elems] bf16 of (-2*c).
__global__ __launch_bounds__(BLOCK, 1) void assign_mfma(
        const float* __restrict__ x,
        const float* __restrict__ cent,
        const float* __restrict__ csq_g,
        float* __restrict__ parts,
        int N, int ppb) {
    extern __shared__ char smem[];
    short* chi = (short*)smem;                       // 16384 shorts
    short* clo = chi + 16384;                        // 16384 shorts
    float* s_csq = (float*)(clo + 16384);            // 256
    float* s_sums = s_csq + 256;                     // 16384
    float* s_cnt = s_sums + 16384;                   // 256

    const int tid = threadIdx.x;

    // ---- stage centroids as -2c hi/lo bf16 in chunked layout ----
    for (int i = tid; i < (K * D) / 4; i += BLOCK) {
        float4 c4 = ((const float4*)cent)[i];
        int elem = i * 4;
        int m = elem >> 6;          // cent index
        int k0 = elem & 63;         // dim
        int g = k0 >> 3, e0 = k0 & 7;   // e0 in {0,4}
        float cv[4] = {c4.x, c4.y, c4.z, c4.w};
        short4v hv, lv;
        #pragma unroll
        for (int j = 0; j < 4; ++j) {
            float v = -2.0f * cv[j];
            unsigned short h = f2bf(v);
            hv[j] = (short)h;
            lv[j] = (short)f2bf(v - bf2f(h));
        }
        int dst = (g * 256 + m) * 8 + e0;
        *(short4v*)&chi[dst] = hv;
        *(short4v*)&clo[dst] = lv;
    }
    if (tid < K) s_csq[tid] = csq_g[tid];
    for (int i = tid; i < K * D; i += BLOCK) s_sums[i] = 0.0f;
    if (tid < K) s_cnt[tid] = 0.0f;
    __syncthreads();

    const int wv = tid >> 6;
    const int lane = tid & 63;
    const int c15 = lane & 15;        // B col (point) / A row (cent-in-tile)
    const int g4 = lane >> 4;         // k-chunk group / cent quadrant

    const int base = blockIdx.x * ppb;
    int lim = base + ppb;
    if (lim > N) lim = N;
    const int ngroups = (lim > base) ? ((lim - base + 15) >> 4) : 0;

    for (int grp = wv; grp < ngroups; grp += BLOCK / 64) {
        const int p0 = base + grp * 16;
        int prow = p0 + c15;
        int pr = (prow < lim) ? prow : (lim - 1);
        const float* xr = x + (size_t)pr * D;

        // ---- B fragments: this lane's point row, chunks g4 (s=0), 4+g4 ----
        bf16x8 bh[2], bl[2];
        #pragma unroll
        for (int s = 0; s < 2; ++s) {
            const float4* xp4 = (const float4*)(xr + s * 32 + g4 * 8);
            float4 u0 = xp4[0], u1 = xp4[1];
            float xv[8] = {u0.x, u0.y, u0.z, u0.w, u1.x, u1.y, u1.z, u1.w};
            #pragma unroll
            for (int e = 0; e < 8; ++e) {
                unsigned short h = f2bf(xv[e]);
                bh[s][e] = (short)h;
                bl[s][e] = (short)f2bf(xv[e] - bf2f(h));
            }
        }

        // ---- all 16 cent-tiles of MFMA (acc stays live: 64 VGPR) ----
        f32x4 acc[16];
        #pragma unroll
        for (int t = 0; t < 16; ++t) {
            f32x4 z = {0.f, 0.f, 0.f, 0.f};
            acc[t] = z;
            #pragma unroll
            for (int s = 0; s < 2; ++s) {
                int ai = (((s * 4 + g4) * 256) + t * 16 + c15) * 8;
                bf16x8 ah = *(const bf16x8*)&chi[ai];
                bf16x8 al = *(const bf16x8*)&clo[ai];
                acc[t] = __builtin_amdgcn_mfma_f32_16x16x32_bf16(ah, bh[s], acc[t], 0, 0, 0);
                acc[t] = __builtin_amdgcn_mfma_f32_16x16x32_bf16(ah, bl[s], acc[t], 0, 0, 0);
                acc[t] = __builtin_amdgcn_mfma_f32_16x16x32_bf16(al, bh[s], acc[t], 0, 0, 0);
            }
        }

        // ---- pass 1: approximate global min ----
        float gmin = 3.4e38f;
        int gidx = 0;
        #pragma unroll
        for (int t = 0; t < 16; ++t) {
            f32x4 q = *(const f32x4*)&s_csq[t * 16 + (g4 << 2)];
            #pragma unroll
            for (int r = 0; r < 4; ++r) {
                float sc = acc[t][r] + q[r];
                int m = t * 16 + (g4 << 2) + r;
                if (sc < gmin) { gmin = sc; gidx = m; }
            }
        }
        #pragma unroll
        for (int off = 16; off <= 32; off <<= 1) {
            float so = __shfl_xor(gmin, off);
            int io = __shfl_xor(gidx, off);
            if (so < gmin || (so == gmin && io < gidx)) { gmin = so; gidx = io; }
        }

        // ---- pass 2: candidate mask vs FINAL global min ----
        unsigned long long cmask = 0;
        #pragma unroll
        for (int t = 0; t < 16; ++t) {
            f32x4 q = *(const f32x4*)&s_csq[t * 16 + (g4 << 2)];
            #pragma unroll
            for (int r = 0; r < 4; ++r) {
                float sc = acc[t][r] + q[r];
                if (sc <= gmin + EPS) cmask |= 1ull << (t * 4 + r);
            }
        }
        int nb_ = __popcll(cmask);
        nb_ += __shfl_xor(nb_, 16);
        nb_ += __shfl_xor(nb_, 32);

        int bk = gidx;
        if (__any(nb_ >= 2)) {
            // ---- exact fp32 refine: reference formula, fp32 centroids ----
            float xsq = 0.0f;
            #pragma unroll
            for (int d = 0; d < D; ++d) xsq += xr[d] * xr[d];
            float eb = 3.4e38f;
            int em = 0x7fffffff;
            unsigned long long mm = cmask;
            while (mm) {
                int b = __ffsll((unsigned long long)mm) - 1;
                mm &= mm - 1;
                int m = ((b >> 2) << 4) + (g4 << 2) + (b & 3);
                const float* cr = cent + m * D;
                float dot = 0.0f;
                #pragma unroll
                for (int d4 = 0; d4 < D; d4 += 4) {
                    float4 c4 = *(const float4*)(cr + d4);
                    dot += c4.x * xr[d4 + 0];
                    dot += c4.y * xr[d4 + 1];
                    dot += c4.z * xr[d4 + 2];
                    dot += c4.w * xr[d4 + 3];
                }
                float es = xsq - 2.0f * dot + s_csq[m];
                if (es < eb || (es == eb && m < em)) { eb = es; em = m; }
            }
            #pragma unroll
            for (int off = 16; off <= 32; off <<= 1) {
                float so = __shfl_xor(eb, off);
                int io = __shfl_xor(em, off);
                if (so < eb || (so == eb && io < em)) { eb = so; em = io; }
            }
            bk = em;
        }

        // ---- accumulate the group's points (lane = dim) ----
        #pragma unroll 1
        for (int i = 0; i < 16; ++i) {
            int p = p0 + i;
            if (p >= lim) break;
            int mk = __shfl(bk, i);
            float xv = x[(size_t)p * D + lane];
            atomicAdd(&s_sums[mk * D + lane], xv);
            if (lane == 0) atomicAdd(&s_cnt[mk], 1.0f);
        }
    }

    __syncthreads();
    // ---- flush block partials ----
    float* part = parts + (size_t)blockIdx.x * PART_STRIDE;
    for (int i = tid; i < K * D; i += BLOCK) part[i] = s_sums[i];
    if (tid < K) part[K * D + tid] = s_cnt[tid];
}

// ---------------------------------------------------------------------------
// fused reduce + finalize: one cent per block, 256 threads (4 slices x 64 dims)
__global__ void finalize2(float* __restrict__ cent,
                          const float* __restrict__ parts,
                          float* __restrict__ csq_g,
                          int nb) {
    __shared__ float tmp[4][64];
    __shared__ float tcnt[4];
    int k = blockIdx.x;
    int sl = threadIdx.x >> 6;
    int d = threadIdx.x & 63;
    float s = 0.0f, c = 0.0f;
    for (int b = sl; b < nb; b += 4) {
        const float* pb = parts + (size_t)b * PART_STRIDE;
        s += pb[k * D + d];
        c += pb[K * D + k];
    }
    tmp[sl][d] = s;
    if (d == 0) tcnt[sl] = c;
    __syncthreads();
    if (sl == 0) {
        float st = tmp[0][d] + tmp[1][d] + tmp[2][d] + tmp[3][d];
        float ct = tcnt[0] + tcnt[1] + tcnt[2] + tcnt[3];
        float oldc = cent[k * D + d];
        float nc = (ct > 0.0f) ? (st / ct) : oldc;
        cent[k * D + d] = nc;
        float v = nc * nc;
        #pragma unroll
        for (int off = 32; off > 0; off >>= 1) v += __shfl_down(v, off);
        if (d == 0) csq_g[k] = v;
    }
}

// ---------------------------------------------------------------------------
extern "C" void kernel_launch(void* const* d_in, const int* in_sizes, int n_in,
                              void* d_out, int out_size, void* d_ws, size_t ws_size,
                              hipStream_t stream) {
    const float* x = (const float*)d_in[0];
    const int* init_idx = (const int*)d_in[1];

    int N = in_sizes[0] / D;

    float* cent = (float*)d_out;

    // ws layout: parts[nb][PART_STRIDE] | csq[K]
    int nb = NB_MAX;
    size_t need = ((size_t)NB_MAX * PART_STRIDE + K) * sizeof(float);
    if (ws_size < need) {
        size_t avail = (ws_size > (size_t)K * sizeof(float))
                           ? ws_size - (size_t)K * sizeof(float) : 0;
        nb = (int)(avail / (PART_STRIDE * sizeof(float)));
        if (nb < 1) nb = 1;
    }
    float* parts = (float*)d_ws;
    float* csq = parts + (size_t)nb * PART_STRIDE;

    hipFuncSetAttribute(reinterpret_cast<const void*>(assign_mfma),
                        hipFuncAttributeMaxDynamicSharedMemorySize, SMEM_BYTES);

    init_gather<<<dim3(K), dim3(64), 0, stream>>>(x, init_idx, cent, csq);

    int ppb = (N + nb - 1) / nb;
    for (int it = 0; it < ITERS; ++it) {
        assign_mfma<<<dim3(nb), dim3(BLOCK), SMEM_BYTES, stream>>>(
            x, cent, csq, parts, N, ppb);
        finalize2<<<dim3(K), dim3(256), 0, stream>>>(cent, parts, csq, nb);
    }
}

// Round 8
// 2433.310 us; speedup vs baseline: 1.8434x; 1.0559x over previous
//
#include <hip/hip_runtime.h>

// k-means (Lloyd), N=500000 D=64 K=256 ITERS=10, fp32.
// Round 8: latency fixes on the round-6/7 MFMA design (which passed at
// 2569us but was latency-bound: MfmaUtil 7.5%, VALUBusy 17%, all pipes idle).
//  - owner-lane accumulation: each lane atomically adds its own 16 registered
//    dims to s_sums[bk][*] (no bk shuffle, no x reload -> kills the ~14k-cyc
//    serial chain per group).
//  - 2-group interleave per wave iteration (2x ILP; A-frag LDS reads shared).
//  - sums rows padded to 66 floats (atomic bank spread).
// Scoring math/refine identical to round 6/7 (proven numerics).

#define D 64
#define K 256
#define ITERS 10
#define BLOCK 512
#define NB_MAX 256
#define EPS 2e-2f
#define SPAD 66
#define PART_STRIDE (K * D + K)   // 16640 floats per block partial
// LDS: chi 32KB + clo 32KB + csq 1KB + sums(padded) 66KB + cnt 1KB = 132KB
#define SMEM_BYTES (32768 * 2 + (256 + 256 * SPAD + 256) * 4)

typedef __attribute__((ext_vector_type(8))) short bf16x8;
typedef __attribute__((ext_vector_type(4))) float f32x4;
typedef __attribute__((ext_vector_type(4))) short short4v;

__device__ __forceinline__ unsigned short f2bf(float f) {
    unsigned u = __builtin_bit_cast(unsigned, f);
    u = u + 0x7FFFu + ((u >> 16) & 1u);   // RNE
    return (unsigned short)(u >> 16);
}
__device__ __forceinline__ float bf2f(unsigned short h) {
    unsigned u = ((unsigned)h) << 16;
    return __builtin_bit_cast(float, u);
}

// ---------------------------------------------------------------------------
__global__ void init_gather(const float* __restrict__ x,
                            const int* __restrict__ idx,
                            float* __restrict__ cent,
                            float* __restrict__ csq) {
    int k = blockIdx.x;
    int d = threadIdx.x;
    float v = x[(size_t)idx[k] * D + d];
    cent[k * D + d] = v;
    float s = v * v;
    #pragma unroll
    for (int off = 32; off > 0; off >>= 1) s += __shfl_down(s, off);
    if (d == 0) csq[k] = s;
}

// ---------------------------------------------------------------------------
// score -> argmin (+ exact fp32 refine on near-ties). Identical numerics to
// round 6/7. Returns bk (same value on all 4 replica lanes of the point).
__device__ __forceinline__ int resolve_bk(
        const f32x4 (&acc)[16], const float* __restrict__ s_csq,
        const float* __restrict__ cent, const float* __restrict__ xr,
        int g4) {
    // pass 1: global approx min
    float gmin = 3.4e38f;
    int gidx = 0;
    #pragma unroll
    for (int t = 0; t < 16; ++t) {
        f32x4 q = *(const f32x4*)&s_csq[t * 16 + (g4 << 2)];
        #pragma unroll
        for (int r = 0; r < 4; ++r) {
            float sc = acc[t][r] + q[r];
            int m = t * 16 + (g4 << 2) + r;
            if (sc < gmin) { gmin = sc; gidx = m; }
        }
    }
    #pragma unroll
    for (int off = 16; off <= 32; off <<= 1) {
        float so = __shfl_xor(gmin, off);
        int io = __shfl_xor(gidx, off);
        if (so < gmin || (so == gmin && io < gidx)) { gmin = so; gidx = io; }
    }
    // pass 2: candidate mask vs FINAL min
    unsigned long long cmask = 0;
    #pragma unroll
    for (int t = 0; t < 16; ++t) {
        f32x4 q = *(const f32x4*)&s_csq[t * 16 + (g4 << 2)];
        #pragma unroll
        for (int r = 0; r < 4; ++r) {
            float sc = acc[t][r] + q[r];
            if (sc <= gmin + EPS) cmask |= 1ull << (t * 4 + r);
        }
    }
    int nb_ = __popcll(cmask);
    nb_ += __shfl_xor(nb_, 16);
    nb_ += __shfl_xor(nb_, 32);

    int bk = gidx;
    if (__any(nb_ >= 2)) {
        float xsq = 0.0f;
        #pragma unroll
        for (int d = 0; d < D; ++d) xsq += xr[d] * xr[d];
        float eb = 3.4e38f;
        int em = 0x7fffffff;
        unsigned long long mm = cmask;
        while (mm) {
            int b = __ffsll((unsigned long long)mm) - 1;
            mm &= mm - 1;
            int m = ((b >> 2) << 4) + (g4 << 2) + (b & 3);
            const float* cr = cent + m * D;
            float dot = 0.0f;
            #pragma unroll
            for (int d4 = 0; d4 < D; d4 += 4) {
                float4 c4 = *(const float4*)(cr + d4);
                dot += c4.x * xr[d4 + 0];
                dot += c4.y * xr[d4 + 1];
                dot += c4.z * xr[d4 + 2];
                dot += c4.w * xr[d4 + 3];
            }
            float es = xsq - 2.0f * dot + s_csq[m];
            if (es < eb || (es == eb && m < em)) { eb = es; em = m; }
        }
        #pragma unroll
        for (int off = 16; off <= 32; off <<= 1) {
            float so = __shfl_xor(eb, off);
            int io = __shfl_xor(em, off);
            if (so < eb || (so == eb && io < em)) { eb = so; em = io; }
        }
        bk = em;
    }
    return bk;
}

// ---------------------------------------------------------------------------
// fused assign (MFMA + exact refine) + owner-lane accumulate.
// chi/clo LDS layout: [8 k-chunks][256 cents][8 elems] bf16 of (-2*c).
__global__ __launch_bounds__(BLOCK, 1) void assign_mfma(
        const float* __restrict__ x,
        const float* __restrict__ cent,
        const float* __restrict__ csq_g,
        float* __restrict__ parts,
        int N, int ppb) {
    extern __shared__ char smem[];
    short* chi = (short*)smem;                       // 16384 shorts
    short* clo = chi + 16384;                        // 16384 shorts
    float* s_csq = (float*)(clo + 16384);            // 256
    float* s_sums = s_csq + 256;                     // 256*SPAD
    float* s_cnt = s_sums + 256 * SPAD;              // 256

    const int tid = threadIdx.x;

    // ---- stage centroids as -2c hi/lo bf16 in chunked layout ----
    for (int i = tid; i < (K * D) / 4; i += BLOCK) {
        float4 c4 = ((const float4*)cent)[i];
        int elem = i * 4;
        int m = elem >> 6;
        int k0 = elem & 63;
        int g = k0 >> 3, e0 = k0 & 7;
        float cv[4] = {c4.x, c4.y, c4.z, c4.w};
        short4v hv, lv;
        #pragma unroll
        for (int j = 0; j < 4; ++j) {
            float v = -2.0f * cv[j];
            unsigned short h = f2bf(v);
            hv[j] = (short)h;
            lv[j] = (short)f2bf(v - bf2f(h));
        }
        int dst = (g * 256 + m) * 8 + e0;
        *(short4v*)&chi[dst] = hv;
        *(short4v*)&clo[dst] = lv;
    }
    if (tid < K) s_csq[tid] = csq_g[tid];
    for (int i = tid; i < 256 * SPAD; i += BLOCK) s_sums[i] = 0.0f;
    if (tid < K) s_cnt[tid] = 0.0f;
    __syncthreads();

    const int wv = tid >> 6;
    const int lane = tid & 63;
    const int c15 = lane & 15;        // point-in-group / cent-row-in-tile
    const int g4 = lane >> 4;         // k-chunk group / cent quadrant

    const int base = blockIdx.x * ppb;
    int lim = base + ppb;
    if (lim > N) lim = N;
    const int ngroups = (lim > base) ? ((lim - base + 15) >> 4) : 0;

    #pragma unroll 1
    for (int g0 = wv; g0 < ngroups; g0 += 16) {
        const int gB = g0 + 8;
        const bool hasB = (gB < ngroups);

        int prA = base + g0 * 16 + c15;
        int prB = base + gB * 16 + c15;
        const bool vA = prA < lim;
        const bool vB = hasB && (prB < lim);
        const float* xrA = x + (size_t)(vA ? prA : (lim - 1)) * D;
        const float* xrB = x + (size_t)(vB ? prB : (lim - 1)) * D;

        // ---- load both point rows (this lane's 16 dims each) + convert ----
        float xfA[16], xfB[16];
        bf16x8 bhA[2], blA[2], bhB[2], blB[2];
        #pragma unroll
        for (int s = 0; s < 2; ++s) {
            const float4* pa = (const float4*)(xrA + s * 32 + g4 * 8);
            float4 a0 = pa[0], a1 = pa[1];
            xfA[s * 8 + 0] = a0.x; xfA[s * 8 + 1] = a0.y;
            xfA[s * 8 + 2] = a0.z; xfA[s * 8 + 3] = a0.w;
            xfA[s * 8 + 4] = a1.x; xfA[s * 8 + 5] = a1.y;
            xfA[s * 8 + 6] = a1.z; xfA[s * 8 + 7] = a1.w;
            const float4* pb = (const float4*)(xrB + s * 32 + g4 * 8);
            float4 b0 = pb[0], b1 = pb[1];
            xfB[s * 8 + 0] = b0.x; xfB[s * 8 + 1] = b0.y;
            xfB[s * 8 + 2] = b0.z; xfB[s * 8 + 3] = b0.w;
            xfB[s * 8 + 4] = b1.x; xfB[s * 8 + 5] = b1.y;
            xfB[s * 8 + 6] = b1.z; xfB[s * 8 + 7] = b1.w;
        }
        #pragma unroll
        for (int s = 0; s < 2; ++s) {
            #pragma unroll
            for (int e = 0; e < 8; ++e) {
                float va = xfA[s * 8 + e];
                unsigned short ha = f2bf(va);
                bhA[s][e] = (short)ha;
                blA[s][e] = (short)f2bf(va - bf2f(ha));
                float vb = xfB[s * 8 + e];
                unsigned short hb = f2bf(vb);
                bhB[s][e] = (short)hb;
                blB[s][e] = (short)f2bf(vb - bf2f(hb));
            }
        }

        // ---- MFMA: 16 cent-tiles x both groups (A-frags shared) ----
        f32x4 accA[16], accB[16];
        #pragma unroll
        for (int t = 0; t < 16; ++t) {
            f32x4 z = {0.f, 0.f, 0.f, 0.f};
            accA[t] = z; accB[t] = z;
            #pragma unroll
            for (int s = 0; s < 2; ++s) {
                int ai = (((s * 4 + g4) * 256) + t * 16 + c15) * 8;
                bf16x8 ah = *(const bf16x8*)&chi[ai];
                bf16x8 al = *(const bf16x8*)&clo[ai];
                accA[t] = __builtin_amdgcn_mfma_f32_16x16x32_bf16(ah, bhA[s], accA[t], 0, 0, 0);
                accA[t] = __builtin_amdgcn_mfma_f32_16x16x32_bf16(ah, blA[s], accA[t], 0, 0, 0);
                accA[t] = __builtin_amdgcn_mfma_f32_16x16x32_bf16(al, bhA[s], accA[t], 0, 0, 0);
                accB[t] = __builtin_amdgcn_mfma_f32_16x16x32_bf16(ah, bhB[s], accB[t], 0, 0, 0);
                accB[t] = __builtin_amdgcn_mfma_f32_16x16x32_bf16(ah, blB[s], accB[t], 0, 0, 0);
                accB[t] = __builtin_amdgcn_mfma_f32_16x16x32_bf16(al, bhB[s], accB[t], 0, 0, 0);
            }
        }

        // ---- argmin (+refine) and owner-lane accumulate, group A ----
        {
            int bk = resolve_bk(accA, s_csq, cent, xrA, g4);
            if (vA) {
                #pragma unroll
                for (int s = 0; s < 2; ++s) {
                    #pragma unroll
                    for (int e = 0; e < 8; ++e)
                        atomicAdd(&s_sums[bk * SPAD + s * 32 + g4 * 8 + e],
                                  xfA[s * 8 + e]);
                }
                if (g4 == 0) atomicAdd(&s_cnt[bk], 1.0f);
            }
        }
        // ---- group B ----
        if (hasB) {
            int bk = resolve_bk(accB, s_csq, cent, xrB, g4);
            if (vB) {
                #pragma unroll
                for (int s = 0; s < 2; ++s) {
                    #pragma unroll
                    for (int e = 0; e < 8; ++e)
                        atomicAdd(&s_sums[bk * SPAD + s * 32 + g4 * 8 + e],
                                  xfB[s * 8 + e]);
                }
                if (g4 == 0) atomicAdd(&s_cnt[bk], 1.0f);
            }
        }
    }

    __syncthreads();
    // ---- flush block partials (unpad) ----
    float* part = parts + (size_t)blockIdx.x * PART_STRIDE;
    for (int i = tid; i < K * D; i += BLOCK) {
        int k = i >> 6, d = i & 63;
        part[i] = s_sums[k * SPAD + d];
    }
    if (tid < K) part[K * D + tid] = s_cnt[tid];
}

// ---------------------------------------------------------------------------
// fused reduce + finalize: one cent per block, 256 threads (4 slices x 64 dims)
__global__ void finalize2(float* __restrict__ cent,
                          const float* __restrict__ parts,
                          float* __restrict__ csq_g,
                          int nb) {
    __shared__ float tmp[4][64];
    __shared__ float tcnt[4];
    int k = blockIdx.x;
    int sl = threadIdx.x >> 6;
    int d = threadIdx.x & 63;
    float s = 0.0f, c = 0.0f;
    for (int b = sl; b < nb; b += 4) {
        const float* pb = parts + (size_t)b * PART_STRIDE;
        s += pb[k * D + d];
        c += pb[K * D + k];
    }
    tmp[sl][d] = s;
    if (d == 0) tcnt[sl] = c;
    __syncthreads();
    if (sl == 0) {
        float st = tmp[0][d] + tmp[1][d] + tmp[2][d] + tmp[3][d];
        float ct = tcnt[0] + tcnt[1] + tcnt[2] + tcnt[3];
        float oldc = cent[k * D + d];
        float nc = (ct > 0.0f) ? (st / ct) : oldc;
        cent[k * D + d] = nc;
        float v = nc * nc;
        #pragma unroll
        for (int off = 32; off > 0; off >>= 1) v += __shfl_down(v, off);
        if (d == 0) csq_g[k] = v;
    }
}

// ---------------------------------------------------------------------------
extern "C" void kernel_launch(void* const* d_in, const int* in_sizes, int n_in,
                              void* d_out, int out_size, void* d_ws, size_t ws_size,
                              hipStream_t stream) {
    const float* x = (const float*)d_in[0];
    const int* init_idx = (const int*)d_in[1];

    int N = in_sizes[0] / D;

    float* cent = (float*)d_out;

    // ws layout: parts[nb][PART_STRIDE] | csq[K]
    int nb = NB_MAX;
    size_t need = ((size_t)NB_MAX * PART_STRIDE + K) * sizeof(float);
    if (ws_size < need) {
        size_t avail = (ws_size > (size_t)K * sizeof(float))
                           ? ws_size - (size_t)K * sizeof(float) : 0;
        nb = (int)(avail / (PART_STRIDE * sizeof(float)));
        if (nb < 1) nb = 1;
    }
    float* parts = (float*)d_ws;
    float* csq = parts + (size_t)nb * PART_STRIDE;

    hipFuncSetAttribute(reinterpret_cast<const void*>(assign_mfma),
                        hipFuncAttributeMaxDynamicSharedMemorySize, SMEM_BYTES);

    init_gather<<<dim3(K), dim3(64), 0, stream>>>(x, init_idx, cent, csq);

    int ppb = (N + nb - 1) / nb;
    for (int it = 0; it < ITERS; ++it) {
        assign_mfma<<<dim3(nb), dim3(BLOCK), SMEM_BYTES, stream>>>(
            x, cent, csq, parts, N, ppb);
        finalize2<<<dim3(K), dim3(256), 0, stream>>>(cent, parts, csq, nb);
    }
}